// Round 1
// baseline (216.186 us; speedup 1.0000x reference)
//
#include <hip/hip_runtime.h>

#define DIM 512
#define HH  1024
#define NB  64
#define NV  64

// ws layout (floats):
//   ctx   [64][1024]  @ 0        ((state+action)@Wx + b1)
//   cause [64][1024]  @ 65536    (embed@Wc)
//   effT  [1024][64]  @ 131072   (embed@We, TRANSPOSED: effT[h][j])

static __device__ __forceinline__ float fast_gelu(float x) {
    // gelu(x) ~= x * sigmoid(1.5957691216*x + 0.0713548162*x^3)
    // exp(-t) = exp2(-t*log2e); fold -log2e into the polynomial coeffs.
    const float C1 = -0.0713548162f * 1.4426950408889634f;
    const float C0 = -1.5957691216f * 1.4426950408889634f;
    float x2 = x * x;
    float u  = x * fmaf(C1, x2, C0);          // = -log2e * (2t)
    float e  = __builtin_amdgcn_exp2f(u);     // exp(-2t)
    return x * __builtin_amdgcn_rcpf(1.0f + e);
}

extern "C" __global__ __launch_bounds__(256)
void cgl_prep(const float* __restrict__ state, const float* __restrict__ action,
              const float* __restrict__ embed, const float* __restrict__ W1,
              const float* __restrict__ b1, float* __restrict__ ws)
{
    __shared__ float arow[4][DIM];
    const int m   = blockIdx.x >> 4;   // 0=cause, 1=effect, 2=ctx
    const int rg  = blockIdx.x & 15;   // row group (4 rows)
    const int tid = threadIdx.x;

    for (int idx = tid; idx < 4 * DIM; idx += 256) {
        int r = idx >> 9, k = idx & (DIM - 1);
        int row = rg * 4 + r;
        float v = (m == 2) ? (state[row * DIM + k] + action[row * DIM + k])
                           : embed[row * DIM + k];
        arow[r][k] = v;
    }
    __syncthreads();

    const float* Wm = W1 + m * DIM * HH;
    const int c = tid * 4;
    float4 acc0 = {0,0,0,0}, acc1 = {0,0,0,0}, acc2 = {0,0,0,0}, acc3 = {0,0,0,0};
    for (int k = 0; k < DIM; ++k) {
        const float4 w = *reinterpret_cast<const float4*>(Wm + k * HH + c);
        float a0 = arow[0][k], a1 = arow[1][k], a2 = arow[2][k], a3 = arow[3][k];
        acc0.x = fmaf(a0, w.x, acc0.x); acc0.y = fmaf(a0, w.y, acc0.y);
        acc0.z = fmaf(a0, w.z, acc0.z); acc0.w = fmaf(a0, w.w, acc0.w);
        acc1.x = fmaf(a1, w.x, acc1.x); acc1.y = fmaf(a1, w.y, acc1.y);
        acc1.z = fmaf(a1, w.z, acc1.z); acc1.w = fmaf(a1, w.w, acc1.w);
        acc2.x = fmaf(a2, w.x, acc2.x); acc2.y = fmaf(a2, w.y, acc2.y);
        acc2.z = fmaf(a2, w.z, acc2.z); acc2.w = fmaf(a2, w.w, acc2.w);
        acc3.x = fmaf(a3, w.x, acc3.x); acc3.y = fmaf(a3, w.y, acc3.y);
        acc3.z = fmaf(a3, w.z, acc3.z); acc3.w = fmaf(a3, w.w, acc3.w);
    }

    float* ctx   = ws;
    float* cause = ws + NB * HH;
    float* effT  = ws + 2 * NB * HH;
    float4 accs[4] = {acc0, acc1, acc2, acc3};
    if (m == 0) {
        #pragma unroll
        for (int r = 0; r < 4; ++r)
            *reinterpret_cast<float4*>(cause + (rg * 4 + r) * HH + c) = accs[r];
    } else if (m == 1) {
        #pragma unroll
        for (int r = 0; r < 4; ++r) {
            int row = rg * 4 + r;
            effT[(c + 0) * NV + row] = accs[r].x;
            effT[(c + 1) * NV + row] = accs[r].y;
            effT[(c + 2) * NV + row] = accs[r].z;
            effT[(c + 3) * NV + row] = accs[r].w;
        }
    } else {
        const float4 bv = *reinterpret_cast<const float4*>(b1 + c);
        #pragma unroll
        for (int r = 0; r < 4; ++r) {
            float4 o = accs[r];
            o.x += bv.x; o.y += bv.y; o.z += bv.z; o.w += bv.w;
            *reinterpret_cast<float4*>(ctx + (rg * 4 + r) * HH + c) = o;
        }
    }
}

extern "C" __global__ __launch_bounds__(256)
void cgl_score(const float* __restrict__ ws, const float* __restrict__ W2,
               const float* __restrict__ b2, float* __restrict__ out)
{
    __shared__ float pre[4][HH];     // 16 KB: ctx[b]+cause[i] per wave
    __shared__ float w2s[HH];        //  4 KB
    __shared__ float eff[64][64];    // 16 KB: effT chunk [dh][j]
    __shared__ float red[4][64];     //  1 KB

    const float* ctx   = ws;
    const float* cause = ws + NB * HH;
    const float* effT  = ws + 2 * NB * HH;

    const int i    = blockIdx.x & 63;
    const int bg   = blockIdx.x >> 6;     // 0..15 (group of 4 b's)
    const int tid  = threadIdx.x;
    const int wave = tid >> 6;
    const int lane = tid & 63;

    for (int idx = tid; idx < 4 * HH; idx += 256) {
        int w = idx >> 10, h = idx & (HH - 1);
        pre[w][h] = ctx[(bg * 4 + w) * HH + h] + cause[i * HH + h];
    }
    for (int h = tid; h < HH; h += 256) w2s[h] = W2[h];

    float acc = 0.0f;
    for (int hc = 0; hc < 16; ++hc) {
        __syncthreads();   // also covers initial pre/w2s fill
        {   // stage 64 rows of effT (4096 floats) as float4
            const float4* src = reinterpret_cast<const float4*>(effT + hc * 64 * 64);
            float4* dst = reinterpret_cast<float4*>(&eff[0][0]);
            for (int idx = tid; idx < 1024; idx += 256) dst[idx] = src[idx];
        }
        __syncthreads();
        #pragma unroll
        for (int dh = 0; dh < 64; ++dh) {
            const int h = hc * 64 + dh;
            float x = pre[wave][h] + eff[dh][lane];   // broadcast + 2-way (free)
            acc = fmaf(fast_gelu(x), w2s[h], acc);
        }
    }

    float logit = acc + b2[0];
    float s = __builtin_amdgcn_rcpf(
        1.0f + __builtin_amdgcn_exp2f(-1.4426950408889634f * logit));
    red[wave][lane] = s;
    __syncthreads();
    if (wave == 0) {
        float r = (red[0][lane] + red[1][lane] + red[2][lane] + red[3][lane])
                  * (1.0f / 64.0f);
        atomicAdd(&out[i * 64 + lane], r);
    }
}

extern "C" void kernel_launch(void* const* d_in, const int* in_sizes, int n_in,
                              void* d_out, int out_size, void* d_ws, size_t ws_size,
                              hipStream_t stream) {
    const float* state  = (const float*)d_in[0];
    const float* action = (const float*)d_in[1];
    const float* embed  = (const float*)d_in[2];
    const float* W1     = (const float*)d_in[3];
    const float* b1     = (const float*)d_in[4];
    const float* W2     = (const float*)d_in[5];
    const float* b2     = (const float*)d_in[6];
    float* ws = (float*)d_ws;

    hipMemsetAsync(d_out, 0, out_size * sizeof(float), stream);
    cgl_prep<<<48, 256, 0, stream>>>(state, action, embed, W1, b1, ws);
    cgl_score<<<64 * 16, 256, 0, stream>>>(ws, W2, b2, (float*)d_out);
}

// Round 4
// 201.745 us; speedup vs baseline: 1.0716x; 1.0716x over previous
//
#include <hip/hip_runtime.h>

#define DIM 512
#define HH  1024
#define NB  64
#define NV  64

// ws layout (floats):
//   ctx   [64][1024]  @ 0        ((state+action)@Wx + b1)
//   cause [64][1024]  @ 65536    (embed@Wc)
//   effT  [1024][64]  @ 131072   (embed@We, TRANSPOSED: effT[h][j])

static __device__ __forceinline__ float fast_gelu(float x) {
    // gelu(x) ~= x * sigmoid(1.5957691216*x + 0.0713548162*x^3)
    const float C1 = -0.0713548162f * 1.4426950408889634f;
    const float C0 = -1.5957691216f * 1.4426950408889634f;
    float x2 = x * x;
    float u  = x * fmaf(C1, x2, C0);
    float e  = __builtin_amdgcn_exp2f(u);
    return x * __builtin_amdgcn_rcpf(1.0f + e);
}

// K-split prep: grid = 3 m  x 16 rowgroups x 8 k-chunks = 384 blocks.
// Each block does a 64-deep k-slice and atomicAdds partial dots into ws.
extern "C" __global__ __launch_bounds__(256)
void cgl_prep(const float* __restrict__ state, const float* __restrict__ action,
              const float* __restrict__ embed, const float* __restrict__ W1,
              const float* __restrict__ b1, float* __restrict__ ws)
{
    __shared__ float arow[4][64];
    const int m   = blockIdx.x >> 7;       // 0=cause, 1=effect, 2=ctx
    const int rg  = (blockIdx.x >> 3) & 15;
    const int kc  = blockIdx.x & 7;
    const int tid = threadIdx.x;

    {   // stage 4 rows x 64 k's (exactly 256 values)
        int r = tid >> 6, kk = tid & 63;
        int row = rg * 4 + r, k = kc * 64 + kk;
        arow[r][kk] = (m == 2) ? (state[row * DIM + k] + action[row * DIM + k])
                               : embed[row * DIM + k];
    }
    __syncthreads();

    const float* Wm = W1 + m * DIM * HH + kc * 64 * HH;
    const int c = tid * 4;
    float4 acc0 = {0,0,0,0}, acc1 = {0,0,0,0}, acc2 = {0,0,0,0}, acc3 = {0,0,0,0};
    #pragma unroll 4
    for (int kk = 0; kk < 64; ++kk) {
        const float4 w = *reinterpret_cast<const float4*>(Wm + kk * HH + c);
        float a0 = arow[0][kk], a1 = arow[1][kk], a2 = arow[2][kk], a3 = arow[3][kk];
        acc0.x = fmaf(a0, w.x, acc0.x); acc0.y = fmaf(a0, w.y, acc0.y);
        acc0.z = fmaf(a0, w.z, acc0.z); acc0.w = fmaf(a0, w.w, acc0.w);
        acc1.x = fmaf(a1, w.x, acc1.x); acc1.y = fmaf(a1, w.y, acc1.y);
        acc1.z = fmaf(a1, w.z, acc1.z); acc1.w = fmaf(a1, w.w, acc1.w);
        acc2.x = fmaf(a2, w.x, acc2.x); acc2.y = fmaf(a2, w.y, acc2.y);
        acc2.z = fmaf(a2, w.z, acc2.z); acc2.w = fmaf(a2, w.w, acc2.w);
        acc3.x = fmaf(a3, w.x, acc3.x); acc3.y = fmaf(a3, w.y, acc3.y);
        acc3.z = fmaf(a3, w.z, acc3.z); acc3.w = fmaf(a3, w.w, acc3.w);
    }

    float* ctx   = ws;
    float* cause = ws + NB * HH;
    float* effT  = ws + 2 * NB * HH;
    float4 accs[4] = {acc0, acc1, acc2, acc3};

    if (m == 2 && kc == 0) {   // add bias exactly once
        const float4 bv = *reinterpret_cast<const float4*>(b1 + c);
        #pragma unroll
        for (int r = 0; r < 4; ++r) {
            accs[r].x += bv.x; accs[r].y += bv.y;
            accs[r].z += bv.z; accs[r].w += bv.w;
        }
    }

    #pragma unroll
    for (int r = 0; r < 4; ++r) {
        const int row = rg * 4 + r;
        if (m == 1) {
            atomicAdd(&effT[(c + 0) * NV + row], accs[r].x);
            atomicAdd(&effT[(c + 1) * NV + row], accs[r].y);
            atomicAdd(&effT[(c + 2) * NV + row], accs[r].z);
            atomicAdd(&effT[(c + 3) * NV + row], accs[r].w);
        } else {
            float* base = ((m == 0) ? cause : ctx) + row * HH + c;
            atomicAdd(base + 0, accs[r].x);
            atomicAdd(base + 1, accs[r].y);
            atomicAdd(base + 2, accs[r].z);
            atomicAdd(base + 3, accs[r].w);
        }
    }
}

// 512 threads = 8 waves: wave = (b_local 0..3) x (h-half 0..1).
// Each wave: lane = j, walks 16 chunks of 32 h within its half.
extern "C" __global__ __launch_bounds__(512, 8)
void cgl_score(const float* __restrict__ ws, const float* __restrict__ W2,
               const float* __restrict__ b2, float* __restrict__ out)
{
    __shared__ float pre[4][HH];       // 16 KB: ctx[b]+cause[i]
    __shared__ float eff[2][32][64];   // 16 KB: eff chunks for both halves
    __shared__ float w2s[HH];          //  4 KB
    __shared__ float red[8][64];       //  2 KB

    const float* ctx   = ws;
    const float* cause = ws + NB * HH;
    const float* effT  = ws + 2 * NB * HH;

    const int i    = blockIdx.x & 63;
    const int bg   = blockIdx.x >> 6;      // 0..15
    const int tid  = threadIdx.x;
    const int wave = tid >> 6;
    const int lane = tid & 63;
    const int bq   = wave & 3;             // local b
    const int hh   = wave >> 2;            // h half (0/1)

    for (int idx = tid; idx < 4 * HH; idx += 512) {
        int w = idx >> 10, h = idx & (HH - 1);
        pre[w][h] = ctx[(bg * 4 + w) * HH + h] + cause[i * HH + h];
    }
    for (int h = tid; h < HH; h += 512) w2s[h] = W2[h];

    float acc = 0.0f;
    const int base_h = hh * 512;
    for (int c = 0; c < 16; ++c) {
        __syncthreads();
        // stage eff rows [q*512 + c*32, +32) for q=0,1: 2*2048 floats = 1024 float4
        for (int idx = tid; idx < 1024; idx += 512) {
            int q = idx >> 9, r = idx & 511;
            reinterpret_cast<float4*>(&eff[q][0][0])[r] =
                reinterpret_cast<const float4*>(effT + (q * 512 + c * 32) * NV)[r];
        }
        __syncthreads();
        #pragma unroll
        for (int dh = 0; dh < 32; ++dh) {
            const int h = base_h + c * 32 + dh;
            float x = pre[bq][h] + eff[hh][dh][lane];
            acc = fmaf(fast_gelu(x), w2s[h], acc);
        }
    }

    red[wave][lane] = acc;
    __syncthreads();
    if (wave < 4) {
        float logit = red[wave][lane] + red[wave + 4][lane] + b2[0];
        float s = __builtin_amdgcn_rcpf(
            1.0f + __builtin_amdgcn_exp2f(-1.4426950408889634f * logit));
        atomicAdd(&out[i * 64 + lane], s * (1.0f / 64.0f));
    }
}

extern "C" void kernel_launch(void* const* d_in, const int* in_sizes, int n_in,
                              void* d_out, int out_size, void* d_ws, size_t ws_size,
                              hipStream_t stream) {
    const float* state  = (const float*)d_in[0];
    const float* action = (const float*)d_in[1];
    const float* embed  = (const float*)d_in[2];
    const float* W1     = (const float*)d_in[3];
    const float* b1     = (const float*)d_in[4];
    const float* W2     = (const float*)d_in[5];
    const float* b2     = (const float*)d_in[6];
    float* ws = (float*)d_ws;

    hipMemsetAsync(d_out, 0, out_size * sizeof(float), stream);
    hipMemsetAsync(d_ws, 0, 3 * NB * HH * sizeof(float), stream);
    cgl_prep<<<384, 256, 0, stream>>>(state, action, embed, W1, b1, ws);
    cgl_score<<<64 * 16, 512, 0, stream>>>(ws, W2, b2, (float*)d_out);
}